// Round 4
// baseline (267.142 us; speedup 1.0000x reference)
//
#include <hip/hip_runtime.h>
#include <hip/hip_bf16.h>
#include <stdint.h>

// ---------------------------------------------------------------------------
// NF4 dequant + linear:  out[M,N] = x[M,K] @ W[N,K]^T + bias
// R4: same fused kernel as R3 (dequant in B-staging), but grid order fixed
// for L3 reuse: blockIdx.x = M-panel (8, fastest) so the 8 blocks sharing a
// widx N-panel are co-resident -> panel re-reads hit Infinity Cache instead
// of HBM (R3 was 1.44 GB HBM refetch = 236 us, exactly measured).
// ---------------------------------------------------------------------------

using short8 = __attribute__((ext_vector_type(8))) short;
using f32x4  = __attribute__((ext_vector_type(4))) float;

#define AS1 __attribute__((address_space(1)))
#define AS3 __attribute__((address_space(3)))

__device__ __forceinline__ void gload16(const void* g, void* l) {
  __builtin_amdgcn_global_load_lds((const AS1 uint32_t*)g, (AS3 uint32_t*)l, 16, 0, 0);
}

__constant__ float NF4_CONST[16] = {
  -1.0f, -0.6961928009986877f, -0.5250730514526367f, -0.39491748809814453f,
  -0.28444138169288635f, -0.18477343022823334f, -0.09105003625154495f, 0.0f,
  0.07958029955625534f, 0.16093020141124725f, 0.24611230194568634f,
  0.33791524171829224f, 0.44070982933044434f, 0.5626170039176941f,
  0.7229568362236023f, 1.0f};

__device__ __forceinline__ ushort f2bf(float f) {
  union { float f; uint32_t u; } v; v.f = f;
  uint32_t r = (v.u + 0x7FFFu + ((v.u >> 16) & 1u)) >> 16;
  return (ushort)r;
}

// ---- Pass A: x f32 -> bf16 ------------------------------------------------
__global__ __launch_bounds__(256) void f32_to_bf16(
    const float* __restrict__ in, ushort* __restrict__ out) {
  const int t = blockIdx.x * 256 + threadIdx.x;
  const int base = t * 8;
  const float4 a = *(const float4*)(in + base);
  const float4 b = *(const float4*)(in + base + 4);
  uint4 o;
  o.x = (uint32_t)f2bf(a.x) | ((uint32_t)f2bf(a.y) << 16);
  o.y = (uint32_t)f2bf(a.z) | ((uint32_t)f2bf(a.w) << 16);
  o.z = (uint32_t)f2bf(b.x) | ((uint32_t)f2bf(b.y) << 16);
  o.w = (uint32_t)f2bf(b.z) | ((uint32_t)f2bf(b.w) << 16);
  *(uint4*)(out + base) = o;
}

// ---- Pass B: fused dequant + 128x128 bf16 GEMM ----------------------------
// C[M,N] = A[M,K] * NF4(widx,absmax)[N,K]^T + bias
// LDS: A-tile 16K | B-tile 16K | pair-LUT 2K.  Swizzle: 16B slot s of row r
// holds logical slot s^(r&7); A staged via pre-swizzled global src +
// gload_lds; B staged via pre-swizzled widx src + linear ds_write (identical
// phys layout).  Reads use the matching XOR (0 bank conflicts, R1-verified).
#define BM 128
#define BN 128
#define BKK 64

// dequant 2 elems: pair-LUT lookup, scale, truncate-pack to bf16x2
#define DQ2(dst, ia, ib, s) do {                                          \
  float2 _c = lut2[(ia) | ((ib) << 4)];                                   \
  uint32_t _u0 = __builtin_bit_cast(uint32_t, _c.x * (s));                \
  uint32_t _u1 = __builtin_bit_cast(uint32_t, _c.y * (s));                \
  dst = (_u0 >> 16) | (_u1 & 0xffff0000u);                                \
} while (0)

__global__ __launch_bounds__(256, 2) void gemm_fused(
    const ushort* __restrict__ A, const int* __restrict__ widx,
    const float* __restrict__ absmax, const float* __restrict__ bias,
    float* __restrict__ C, const int M, const int N, const int K) {
  __shared__ char lds[32768 + 2048];
  float2* lut2 = (float2*)(lds + 32768);
  const int tid  = threadIdx.x;
  const int wid  = tid >> 6;
  const int lane = tid & 63;
  // R4: M-panel on x (fastest-varying) -> the 8 blocks of one N-panel are
  // dispatched consecutively and co-resident -> widx panel L3/L2 reuse.
  const int row0 = blockIdx.x * BM;   // M panel (x output rows)
  const int col0 = blockIdx.y * BN;   // N panel (weight rows)
  const int wr = wid >> 1, wc = wid & 1;
  const int KB = K >> 6;              // absmax blocks per weight row

  // pair-LUT init: entry p=(i0|i1<<4) -> (code[i0], code[i1])
  lut2[tid] = make_float2(NF4_CONST[tid & 15], NF4_CONST[tid >> 4]);

  // per-thread staging constants (pre-swizzled source, rule #21)
  const ushort* gsrcA[4];
  const int*    wsrc[4];
  const float*  asrc[4];
  int bdst[4];
#pragma unroll
  for (int i = 0; i < 4; ++i) {
    const int u = tid + i * 256;
    const int r = u >> 3;
    const int sl = (u & 7) ^ (r & 7);
    gsrcA[i] = A + (size_t)(row0 + r) * K + sl * 8;
    wsrc[i]  = widx + (size_t)(col0 + r) * K + sl * 8;
    asrc[i]  = absmax + (size_t)(col0 + r) * KB;
    bdst[i]  = 16384 + i * 4096 + tid * 16;
  }

  // LDS read byte-offsets (match the write swizzle)
  int offA[2][4], offB[2][4];
#pragma unroll
  for (int ks = 0; ks < 2; ++ks) {
#pragma unroll
    for (int m = 0; m < 4; ++m) {
      const int ra = wr * 64 + m * 16 + (lane & 15);
      offA[ks][m] = ra * 128 + (((ks * 4 + (lane >> 4)) ^ (ra & 7)) * 16);
      const int rb = wc * 64 + m * 16 + (lane & 15);
      offB[ks][m] = 16384 + rb * 128 + (((ks * 4 + (lane >> 4)) ^ (rb & 7)) * 16);
    }
  }

  f32x4 acc[4][4] = {};

  // prefetch K-step 0 widx + absmax into registers
  int4 q0[4], q1[4]; float sc[4];
#pragma unroll
  for (int i = 0; i < 4; ++i) {
    q0[i] = *(const int4*)(wsrc[i]);
    q1[i] = *(const int4*)(wsrc[i] + 4);
    sc[i] = asrc[i][0];
  }
  __syncthreads();   // lut2 visible before first use

  for (int kt = 0; kt < K; kt += BKK) {
    // A stage (async direct-to-LDS)
#pragma unroll
    for (int i = 0; i < 4; ++i)
      gload16(gsrcA[i] + kt, lds + i * 4096 + wid * 1024);
    // B stage: dequant prefetched registers -> swizzled LDS
#pragma unroll
    for (int i = 0; i < 4; ++i) {
      uint4 v;
      DQ2(v.x, q0[i].x, q0[i].y, sc[i]);
      DQ2(v.y, q0[i].z, q0[i].w, sc[i]);
      DQ2(v.z, q1[i].x, q1[i].y, sc[i]);
      DQ2(v.w, q1[i].z, q1[i].w, sc[i]);
      *(uint4*)(lds + bdst[i]) = v;
    }
    __syncthreads();  // drains gload_lds (vmcnt) + ds_writes (lgkm)

    // T14: issue next K-step's widx/absmax loads; land under the MMA below
    if (kt + BKK < K) {
      const int kn = kt + BKK;
#pragma unroll
      for (int i = 0; i < 4; ++i) {
        q0[i] = *(const int4*)(wsrc[i] + kn);
        q1[i] = *(const int4*)(wsrc[i] + kn + 4);
        sc[i] = asrc[i][kn >> 6];
      }
    }

#pragma unroll
    for (int ks = 0; ks < 2; ++ks) {
      short8 af[4], bv[4];
#pragma unroll
      for (int m = 0; m < 4; ++m) af[m] = *(const short8*)(lds + offA[ks][m]);
#pragma unroll
      for (int n = 0; n < 4; ++n) bv[n] = *(const short8*)(lds + offB[ks][n]);
#pragma unroll
      for (int m = 0; m < 4; ++m)
#pragma unroll
        for (int n = 0; n < 4; ++n)
          acc[m][n] = __builtin_amdgcn_mfma_f32_16x16x32_bf16(
              af[m], bv[n], acc[m][n], 0, 0, 0);
    }
    __syncthreads();
  }

  // epilogue: C/D layout col=lane&15, row=(lane>>4)*4+j (m89-verified)
#pragma unroll
  for (int n = 0; n < 4; ++n) {
    const int gc = col0 + wc * 64 + n * 16 + (lane & 15);
    const float bvadd = bias[gc];
#pragma unroll
    for (int m = 0; m < 4; ++m) {
      const int gr0 = row0 + wr * 64 + m * 16 + ((lane >> 4) * 4);
#pragma unroll
      for (int j = 0; j < 4; ++j)
        C[(size_t)(gr0 + j) * N + gc] = acc[m][n][j] + bvadd;
    }
  }
}

// ---- last-resort fallback (non-conforming shapes): correct but slow -------
__global__ __launch_bounds__(256) void fallback_kernel(
    const float* __restrict__ x, const int* __restrict__ widx,
    const float* __restrict__ absmax, const float* __restrict__ bias,
    float* __restrict__ out, const int M, const int N, const int K) {
  __shared__ float w[4096];
  const int o = blockIdx.x;
  for (int k = threadIdx.x; k < K; k += 256) {
    const long long fi = (long long)o * K + k;
    w[k] = NF4_CONST[widx[fi]] * absmax[fi >> 6];
  }
  __syncthreads();
  for (int m = threadIdx.x; m < M; m += 256) {
    float acc = bias[o];
    const float* xr = x + (size_t)m * K;
    for (int k = 0; k < K; ++k) acc += xr[k] * w[k];
    out[(size_t)m * N + o] = acc;
  }
}

extern "C" void kernel_launch(void* const* d_in, const int* in_sizes, int n_in,
                              void* d_out, int out_size, void* d_ws, size_t ws_size,
                              hipStream_t stream) {
  const float* x      = (const float*)d_in[0];
  const int*   widx   = (const int*)d_in[1];
  const float* absmax = (const float*)d_in[2];
  const float* bias   = (const float*)d_in[3];
  float* out = (float*)d_out;

  const int N = in_sizes[3];                 // 11008
  const int K = in_sizes[1] / N;             // 4096
  const int M = in_sizes[0] / K;             // 1024
  const long long xElems = (long long)M * K;
  const size_t wsNeed = (size_t)xElems * 2;

  if (ws_size >= wsNeed && (M % BM) == 0 && (N % BN) == 0 &&
      (K % BKK) == 0 && (xElems % 2048) == 0) {
    ushort* Xbf = (ushort*)d_ws;
    f32_to_bf16<<<(int)(xElems / (256 * 8)), 256, 0, stream>>>(x, Xbf);
    dim3 grid(M / BM, N / BN);   // x = M-panels (8): panel-mates co-resident
    gemm_fused<<<grid, 256, 0, stream>>>(Xbf, widx, absmax, bias, out, M, N, K);
  } else {
    fallback_kernel<<<N, 256, 0, stream>>>(x, widx, absmax, bias, out, M, N, K);
  }
}

// Round 5
// 167.459 us; speedup vs baseline: 1.5953x; 1.5953x over previous
//
#include <hip/hip_runtime.h>
#include <hip/hip_bf16.h>
#include <stdint.h>

// ---------------------------------------------------------------------------
// NF4 dequant + linear:  out[M,N] = x[M,K] @ W[N,K]^T + bias
// R5: fused dequant GEMM with (1) same-XCD panel-mate dispatch: all 8
// M-panel blocks of one widx N-panel map to ids == n (mod 8) within one
// 64-id window -> same XCD L2 (panel 2MB < 4MB L2) + co-resident; (2)
// 16-entry f32 LUT: 1 entry per bank -> all LDS LUT reads are broadcasts
// (zero bank conflicts by construction).
// ---------------------------------------------------------------------------

using short8 = __attribute__((ext_vector_type(8))) short;
using f32x4  = __attribute__((ext_vector_type(4))) float;

#define AS1 __attribute__((address_space(1)))
#define AS3 __attribute__((address_space(3)))

__device__ __forceinline__ void gload16(const void* g, void* l) {
  __builtin_amdgcn_global_load_lds((const AS1 uint32_t*)g, (AS3 uint32_t*)l, 16, 0, 0);
}

__constant__ float NF4_CONST[16] = {
  -1.0f, -0.6961928009986877f, -0.5250730514526367f, -0.39491748809814453f,
  -0.28444138169288635f, -0.18477343022823334f, -0.09105003625154495f, 0.0f,
  0.07958029955625534f, 0.16093020141124725f, 0.24611230194568634f,
  0.33791524171829224f, 0.44070982933044434f, 0.5626170039176941f,
  0.7229568362236023f, 1.0f};

__device__ __forceinline__ ushort f2bf(float f) {
  union { float f; uint32_t u; } v; v.f = f;
  uint32_t r = (v.u + 0x7FFFu + ((v.u >> 16) & 1u)) >> 16;
  return (ushort)r;
}

// ---- Pass A: x f32 -> bf16 ------------------------------------------------
__global__ __launch_bounds__(256) void f32_to_bf16(
    const float* __restrict__ in, ushort* __restrict__ out) {
  const int t = blockIdx.x * 256 + threadIdx.x;
  const int base = t * 8;
  const float4 a = *(const float4*)(in + base);
  const float4 b = *(const float4*)(in + base + 4);
  uint4 o;
  o.x = (uint32_t)f2bf(a.x) | ((uint32_t)f2bf(a.y) << 16);
  o.y = (uint32_t)f2bf(a.z) | ((uint32_t)f2bf(a.w) << 16);
  o.z = (uint32_t)f2bf(b.x) | ((uint32_t)f2bf(b.y) << 16);
  o.w = (uint32_t)f2bf(b.z) | ((uint32_t)f2bf(b.w) << 16);
  *(uint4*)(out + base) = o;
}

// ---- Pass B: fused dequant + 128x128 bf16 GEMM ----------------------------
// LDS: A-tile 16K | B-tile 16K | LUT 64B.  Swizzle: 16B slot s of row r holds
// logical slot s^(r&7); A staged via pre-swizzled global src + gload_lds;
// B staged via pre-swizzled widx src + dequant + linear ds_write (same phys
// layout).  Reads use the matching XOR (conflict-free, R1-verified).
#define BM 128
#define BN 128
#define BKK 64

// dequant 2 elems via broadcast LUT (1 entry/bank, conflict-free)
#define DQ2(dst, ia, ib, s) do {                                          \
  float _a = lutf[(ia)] * (s);                                            \
  float _b = lutf[(ib)] * (s);                                            \
  dst = (__builtin_bit_cast(uint32_t, _a) >> 16) |                        \
        (__builtin_bit_cast(uint32_t, _b) & 0xffff0000u);                 \
} while (0)

__global__ __launch_bounds__(256, 2) void gemm_fused(
    const ushort* __restrict__ A, const int* __restrict__ widx,
    const float* __restrict__ absmax, const float* __restrict__ bias,
    float* __restrict__ C, const int M, const int N, const int K,
    const int MP, const int NB) {
  __shared__ char lds[32768 + 64];
  float* lutf = (float*)(lds + 32768);
  const int tid  = threadIdx.x;
  const int wid  = tid >> 6;
  const int lane = tid & 63;

  // R5 dispatch map: id = r + 8*(m + MP*q), n = 8q + r.
  // -> all M-panel mates of panel n share id%8 == n%8 (same XCD) and live in
  //    one 64*(MP/8)-id window (co-resident).
  const int r8 = blockIdx.x & 7;
  const int w  = blockIdx.x >> 3;
  const int mP = w % MP;
  const int q  = w / MP;
  const int nP = (q << 3) + r8;
  if (nP >= NB) return;                 // uniform early-exit (padded grid)
  const int row0 = mP * BM;
  const int col0 = nP * BN;
  const int wr = wid >> 1, wc = wid & 1;
  const int KB = K >> 6;

  if (tid < 16) lutf[tid] = NF4_CONST[tid];

  // per-thread staging constants (pre-swizzled source, rule #21)
  const ushort* gsrcA[4];
  const int*    wsrc[4];
  const float*  asrc[4];
  int bdst[4];
#pragma unroll
  for (int i = 0; i < 4; ++i) {
    const int u = tid + i * 256;
    const int rr = u >> 3;
    const int sl = (u & 7) ^ (rr & 7);
    gsrcA[i] = A + (size_t)(row0 + rr) * K + sl * 8;
    wsrc[i]  = widx + (size_t)(col0 + rr) * K + sl * 8;
    asrc[i]  = absmax + (size_t)(col0 + rr) * KB;
    bdst[i]  = 16384 + i * 4096 + tid * 16;
  }

  // LDS read byte-offsets (match the write swizzle)
  int offA[2][4], offB[2][4];
#pragma unroll
  for (int ks = 0; ks < 2; ++ks) {
#pragma unroll
    for (int m = 0; m < 4; ++m) {
      const int ra = wr * 64 + m * 16 + (lane & 15);
      offA[ks][m] = ra * 128 + (((ks * 4 + (lane >> 4)) ^ (ra & 7)) * 16);
      const int rb = wc * 64 + m * 16 + (lane & 15);
      offB[ks][m] = 16384 + rb * 128 + (((ks * 4 + (lane >> 4)) ^ (rb & 7)) * 16);
    }
  }

  f32x4 acc[4][4] = {};

  // prefetch K-step 0 widx + absmax into registers (T14)
  int4 q0[4], q1[4]; float sc[4];
#pragma unroll
  for (int i = 0; i < 4; ++i) {
    q0[i] = *(const int4*)(wsrc[i]);
    q1[i] = *(const int4*)(wsrc[i] + 4);
    sc[i] = asrc[i][0];
  }
  __syncthreads();   // lutf visible before first use

  for (int kt = 0; kt < K; kt += BKK) {
    // A stage (async direct-to-LDS)
#pragma unroll
    for (int i = 0; i < 4; ++i)
      gload16(gsrcA[i] + kt, lds + i * 4096 + wid * 1024);
    // B stage: dequant prefetched registers -> swizzled LDS
#pragma unroll
    for (int i = 0; i < 4; ++i) {
      uint4 v;
      DQ2(v.x, q0[i].x, q0[i].y, sc[i]);
      DQ2(v.y, q0[i].z, q0[i].w, sc[i]);
      DQ2(v.z, q1[i].x, q1[i].y, sc[i]);
      DQ2(v.w, q1[i].z, q1[i].w, sc[i]);
      *(uint4*)(lds + bdst[i]) = v;
    }
    __syncthreads();  // drains gload_lds (vmcnt) + ds_writes (lgkm)

    // T14: issue next K-step's widx/absmax loads; land under the MMA below
    if (kt + BKK < K) {
      const int kn = kt + BKK;
#pragma unroll
      for (int i = 0; i < 4; ++i) {
        q0[i] = *(const int4*)(wsrc[i] + kn);
        q1[i] = *(const int4*)(wsrc[i] + kn + 4);
        sc[i] = asrc[i][kn >> 6];
      }
    }

#pragma unroll
    for (int ks = 0; ks < 2; ++ks) {
      short8 af[4], bv[4];
#pragma unroll
      for (int m = 0; m < 4; ++m) af[m] = *(const short8*)(lds + offA[ks][m]);
#pragma unroll
      for (int n = 0; n < 4; ++n) bv[n] = *(const short8*)(lds + offB[ks][n]);
#pragma unroll
      for (int m = 0; m < 4; ++m)
#pragma unroll
        for (int n = 0; n < 4; ++n)
          acc[m][n] = __builtin_amdgcn_mfma_f32_16x16x32_bf16(
              af[m], bv[n], acc[m][n], 0, 0, 0);
    }
    __syncthreads();
  }

  // epilogue: C/D layout col=lane&15, row=(lane>>4)*4+j (m89-verified)
#pragma unroll
  for (int n = 0; n < 4; ++n) {
    const int gc = col0 + wc * 64 + n * 16 + (lane & 15);
    const float bvadd = bias[gc];
#pragma unroll
    for (int m = 0; m < 4; ++m) {
      const int gr0 = row0 + wr * 64 + m * 16 + ((lane >> 4) * 4);
#pragma unroll
      for (int j = 0; j < 4; ++j)
        C[(size_t)(gr0 + j) * N + gc] = acc[m][n][j] + bvadd;
    }
  }
}

// ---- last-resort fallback (non-conforming shapes): correct but slow -------
__global__ __launch_bounds__(256) void fallback_kernel(
    const float* __restrict__ x, const int* __restrict__ widx,
    const float* __restrict__ absmax, const float* __restrict__ bias,
    float* __restrict__ out, const int M, const int N, const int K) {
  __shared__ float w[4096];
  const int o = blockIdx.x;
  for (int k = threadIdx.x; k < K; k += 256) {
    const long long fi = (long long)o * K + k;
    w[k] = NF4_CONST[widx[fi]] * absmax[fi >> 6];
  }
  __syncthreads();
  for (int m = threadIdx.x; m < M; m += 256) {
    float acc = bias[o];
    const float* xr = x + (size_t)m * K;
    for (int k = 0; k < K; ++k) acc += xr[k] * w[k];
    out[(size_t)m * N + o] = acc;
  }
}

extern "C" void kernel_launch(void* const* d_in, const int* in_sizes, int n_in,
                              void* d_out, int out_size, void* d_ws, size_t ws_size,
                              hipStream_t stream) {
  const float* x      = (const float*)d_in[0];
  const int*   widx   = (const int*)d_in[1];
  const float* absmax = (const float*)d_in[2];
  const float* bias   = (const float*)d_in[3];
  float* out = (float*)d_out;

  const int N = in_sizes[3];                 // 11008
  const int K = in_sizes[1] / N;             // 4096
  const int M = in_sizes[0] / K;             // 1024
  const long long xElems = (long long)M * K;
  const size_t wsNeed = (size_t)xElems * 2;

  if (ws_size >= wsNeed && (M % BM) == 0 && (N % BN) == 0 &&
      (K % BKK) == 0 && (xElems % 2048) == 0) {
    ushort* Xbf = (ushort*)d_ws;
    f32_to_bf16<<<(int)(xElems / (256 * 8)), 256, 0, stream>>>(x, Xbf);
    const int MP = M / BM;                   // 8
    const int NB = N / BN;                   // 86
    const int grid = 8 * MP * ((NB + 7) / 8);  // padded; id->(m,n) in-kernel
    gemm_fused<<<dim3(grid), 256, 0, stream>>>(Xbf, widx, absmax, bias, out,
                                               M, N, K, MP, NB);
  } else {
    fallback_kernel<<<N, 256, 0, stream>>>(x, widx, absmax, bias, out, M, N, K);
  }
}

// Round 6
// 155.408 us; speedup vs baseline: 1.7190x; 1.0775x over previous
//
#include <hip/hip_runtime.h>
#include <hip/hip_bf16.h>
#include <stdint.h>

// ---------------------------------------------------------------------------
// NF4 dequant + linear:  out[M,N] = x[M,K] @ W[N,K]^T + bias
// R6: fused dequant GEMM, counted-wait pipeline:
//  - A-tile double-buffered, staged 1 iteration ahead (gload_lds width16)
//  - NO vmcnt drain in the main loop: barrier1 = lgkmcnt(0)+s_barrier only
//    (A's landing guaranteed by in-order vmem retirement: A(j) older than
//    q(j), whose compiler-inserted wait at DQ2 retires it), barrier2 = raw
//  - widx/absmax reg-prefetch (T14) stays in flight across both barriers
//  - R5's same-XCD panel-mate dispatch + broadcast 16-entry LUT retained
// ---------------------------------------------------------------------------

using short8 = __attribute__((ext_vector_type(8))) short;
using f32x4  = __attribute__((ext_vector_type(4))) float;

#define AS1 __attribute__((address_space(1)))
#define AS3 __attribute__((address_space(3)))

__device__ __forceinline__ void gload16(const void* g, void* l) {
  __builtin_amdgcn_global_load_lds((const AS1 uint32_t*)g, (AS3 uint32_t*)l, 16, 0, 0);
}

__constant__ float NF4_CONST[16] = {
  -1.0f, -0.6961928009986877f, -0.5250730514526367f, -0.39491748809814453f,
  -0.28444138169288635f, -0.18477343022823334f, -0.09105003625154495f, 0.0f,
  0.07958029955625534f, 0.16093020141124725f, 0.24611230194568634f,
  0.33791524171829224f, 0.44070982933044434f, 0.5626170039176941f,
  0.7229568362236023f, 1.0f};

__device__ __forceinline__ ushort f2bf(float f) {
  union { float f; uint32_t u; } v; v.f = f;
  uint32_t r = (v.u + 0x7FFFu + ((v.u >> 16) & 1u)) >> 16;
  return (ushort)r;
}

// ---- Pass A: x f32 -> bf16 ------------------------------------------------
__global__ __launch_bounds__(256) void f32_to_bf16(
    const float* __restrict__ in, ushort* __restrict__ out) {
  const int t = blockIdx.x * 256 + threadIdx.x;
  const int base = t * 8;
  const float4 a = *(const float4*)(in + base);
  const float4 b = *(const float4*)(in + base + 4);
  uint4 o;
  o.x = (uint32_t)f2bf(a.x) | ((uint32_t)f2bf(a.y) << 16);
  o.y = (uint32_t)f2bf(a.z) | ((uint32_t)f2bf(a.w) << 16);
  o.z = (uint32_t)f2bf(b.x) | ((uint32_t)f2bf(b.y) << 16);
  o.w = (uint32_t)f2bf(b.z) | ((uint32_t)f2bf(b.w) << 16);
  *(uint4*)(out + base) = o;
}

// ---- Pass B: fused dequant + 128x128 bf16 GEMM ----------------------------
// LDS: A buf0 16K | A buf1 16K | B 16K | LUT 64B = 49216 B.
// Swizzle (R1-verified): 16B slot s of row r holds logical slot s^(r&7).
#define BM 128
#define BN 128
#define BKK 64

// dequant 2 elems via broadcast LUT (1 entry/bank, conflict-free)
#define DQ2(dst, ia, ib, s) do {                                          \
  float _a = lutf[(ia)] * (s);                                            \
  float _b = lutf[(ib)] * (s);                                            \
  dst = (__builtin_bit_cast(uint32_t, _a) >> 16) |                        \
        (__builtin_bit_cast(uint32_t, _b) & 0xffff0000u);                 \
} while (0)

__global__ __launch_bounds__(256, 3) void gemm_fused(
    const ushort* __restrict__ A, const int* __restrict__ widx,
    const float* __restrict__ absmax, const float* __restrict__ bias,
    float* __restrict__ C, const int M, const int N, const int K,
    const int MP, const int NB) {
  __shared__ char lds[49216];
  float* lutf = (float*)(lds + 49152);
  const int tid  = threadIdx.x;
  const int wid  = tid >> 6;
  const int lane = tid & 63;

  // R5 dispatch map: id = r + 8*(m + MP*q), n = 8q + r  -> panel-mates on
  // one XCD (id%8 fixed) and co-resident (one window).
  const int r8 = blockIdx.x & 7;
  const int w  = blockIdx.x >> 3;
  const int mP = w % MP;
  const int q  = w / MP;
  const int nP = (q << 3) + r8;
  if (nP >= NB) return;                 // whole-block early exit (padded grid)
  const int row0 = mP * BM;
  const int col0 = nP * BN;
  const int wr = wid >> 1, wc = wid & 1;
  const int KB = K >> 6;

  if (tid < 16) lutf[tid] = NF4_CONST[tid];

  // per-thread staging constants (pre-swizzled source, rule #21)
  const ushort* gsrcA[4];
  const int*    wsrc[4];
  const float*  asrc[4];
  int bdst[4];
#pragma unroll
  for (int i = 0; i < 4; ++i) {
    const int u = tid + i * 256;
    const int rr = u >> 3;
    const int sl = (u & 7) ^ (rr & 7);
    gsrcA[i] = A + (size_t)(row0 + rr) * K + sl * 8;
    wsrc[i]  = widx + (size_t)(col0 + rr) * K + sl * 8;
    asrc[i]  = absmax + (size_t)(col0 + rr) * KB;
    bdst[i]  = 32768 + i * 4096 + tid * 16;
  }

  // LDS read byte-offsets (match the write swizzle); A offsets are relative
  // to the active A buffer, B offsets absolute.
  int offA[2][4], offB[2][4];
#pragma unroll
  for (int ks = 0; ks < 2; ++ks) {
#pragma unroll
    for (int m = 0; m < 4; ++m) {
      const int ra = wr * 64 + m * 16 + (lane & 15);
      offA[ks][m] = ra * 128 + (((ks * 4 + (lane >> 4)) ^ (ra & 7)) * 16);
      const int rb = wc * 64 + m * 16 + (lane & 15);
      offB[ks][m] = 32768 + rb * 128 + (((ks * 4 + (lane >> 4)) ^ (rb & 7)) * 16);
    }
  }

  f32x4 acc[4][4] = {};

  // ---- prologue: stage A(0) into buf0, prefetch q(0)/sc(0) ----
#pragma unroll
  for (int i = 0; i < 4; ++i)
    gload16(gsrcA[i], lds + i * 4096 + wid * 1024);
  int4 q0[4], q1[4]; float sc[4];
#pragma unroll
  for (int i = 0; i < 4; ++i) {
    q0[i] = *(const int4*)(wsrc[i]);
    q1[i] = *(const int4*)(wsrc[i] + 4);
    sc[i] = asrc[i][0];
  }
  __syncthreads();   // one-time full drain; lutf + A(0) visible
  int cur = 0;

  for (int kt = 0; kt < K; kt += BKK) {
    // stage A(next) into the other buffer (1 iteration ahead)
    const int ka = (kt + BKK < K) ? kt + BKK : kt;   // clamp keeps count fixed
#pragma unroll
    for (int i = 0; i < 4; ++i)
      gload16(gsrcA[i] + ka, lds + ((cur ^ 1) << 14) + i * 4096 + wid * 1024);
    __builtin_amdgcn_sched_barrier(0);   // pin: A-gloads oldest this iter

    // B stage: dequant q(kt) -> swizzled LDS (compiler waits vmcnt for q here,
    // which also retires the older A(kt) gloads -> barrier1 needs no vmcnt)
#pragma unroll
    for (int i = 0; i < 4; ++i) {
      uint4 v;
      DQ2(v.x, q0[i].x, q0[i].y, sc[i]);
      DQ2(v.y, q0[i].z, q0[i].w, sc[i]);
      DQ2(v.z, q1[i].x, q1[i].y, sc[i]);
      DQ2(v.w, q1[i].z, q1[i].w, sc[i]);
      *(uint4*)(lds + bdst[i]) = v;
    }
    // T14: prefetch next widx/absmax (stays in flight across both barriers)
#pragma unroll
    for (int i = 0; i < 4; ++i) {
      q0[i] = *(const int4*)(wsrc[i] + ka);
      q1[i] = *(const int4*)(wsrc[i] + ka + 4);
      sc[i] = asrc[i][ka >> 6];
    }
    __builtin_amdgcn_sched_barrier(0);

    // barrier 1: B ds_writes visible; A(kt) already landed (see above).
    asm volatile("s_waitcnt lgkmcnt(0)" ::: "memory");
    __builtin_amdgcn_s_barrier();
    __builtin_amdgcn_sched_barrier(0);

    const int abase = cur << 14;
#pragma unroll
    for (int ks = 0; ks < 2; ++ks) {
      short8 af[4], bv[4];
#pragma unroll
      for (int m = 0; m < 4; ++m)
        af[m] = *(const short8*)(lds + abase + offA[ks][m]);
#pragma unroll
      for (int n = 0; n < 4; ++n)
        bv[n] = *(const short8*)(lds + offB[ks][n]);
#pragma unroll
      for (int m = 0; m < 4; ++m)
#pragma unroll
        for (int n = 0; n < 4; ++n)
          acc[m][n] = __builtin_amdgcn_mfma_f32_16x16x32_bf16(
              af[m], bv[n], acc[m][n], 0, 0, 0);
    }
    __builtin_amdgcn_sched_barrier(0);

    // barrier 2: raw — ds_reads all consumed by MFMAs already; no vmcnt drain
    __builtin_amdgcn_s_barrier();
    cur ^= 1;
  }

  // epilogue: C/D layout col=lane&15, row=(lane>>4)*4+j (m89-verified)
#pragma unroll
  for (int n = 0; n < 4; ++n) {
    const int gc = col0 + wc * 64 + n * 16 + (lane & 15);
    const float bvadd = bias[gc];
#pragma unroll
    for (int m = 0; m < 4; ++m) {
      const int gr0 = row0 + wr * 64 + m * 16 + ((lane >> 4) * 4);
#pragma unroll
      for (int j = 0; j < 4; ++j)
        C[(size_t)(gr0 + j) * N + gc] = acc[m][n][j] + bvadd;
    }
  }
}

// ---- last-resort fallback (non-conforming shapes): correct but slow -------
__global__ __launch_bounds__(256) void fallback_kernel(
    const float* __restrict__ x, const int* __restrict__ widx,
    const float* __restrict__ absmax, const float* __restrict__ bias,
    float* __restrict__ out, const int M, const int N, const int K) {
  __shared__ float w[4096];
  const int o = blockIdx.x;
  for (int k = threadIdx.x; k < K; k += 256) {
    const long long fi = (long long)o * K + k;
    w[k] = NF4_CONST[widx[fi]] * absmax[fi >> 6];
  }
  __syncthreads();
  for (int m = threadIdx.x; m < M; m += 256) {
    float acc = bias[o];
    const float* xr = x + (size_t)m * K;
    for (int k = 0; k < K; ++k) acc += xr[k] * w[k];
    out[(size_t)m * N + o] = acc;
  }
}

extern "C" void kernel_launch(void* const* d_in, const int* in_sizes, int n_in,
                              void* d_out, int out_size, void* d_ws, size_t ws_size,
                              hipStream_t stream) {
  const float* x      = (const float*)d_in[0];
  const int*   widx   = (const int*)d_in[1];
  const float* absmax = (const float*)d_in[2];
  const float* bias   = (const float*)d_in[3];
  float* out = (float*)d_out;

  const int N = in_sizes[3];                 // 11008
  const int K = in_sizes[1] / N;             // 4096
  const int M = in_sizes[0] / K;             // 1024
  const long long xElems = (long long)M * K;
  const size_t wsNeed = (size_t)xElems * 2;

  if (ws_size >= wsNeed && (M % BM) == 0 && (N % BN) == 0 &&
      (K % BKK) == 0 && (xElems % 2048) == 0) {
    ushort* Xbf = (ushort*)d_ws;
    f32_to_bf16<<<(int)(xElems / (256 * 8)), 256, 0, stream>>>(x, Xbf);
    const int MP = M / BM;                   // 8
    const int NB = N / BN;                   // 86
    const int grid = 8 * MP * ((NB + 7) / 8);  // padded; id->(m,n) in-kernel
    gemm_fused<<<dim3(grid), 256, 0, stream>>>(Xbf, widx, absmax, bias, out,
                                               M, N, K, MP, NB);
  } else {
    fallback_kernel<<<N, 256, 0, stream>>>(x, widx, absmax, bias, out, M, N, K);
  }
}